// Round 3
// baseline (6244.061 us; speedup 1.0000x reference)
//
#include <hip/hip_runtime.h>
#include <stdint.h>
#include <stddef.h>

typedef uint16_t u16_t;
typedef uint32_t u32_t;
typedef short s16x8 __attribute__((ext_vector_type(8)));
typedef uint16_t u16x4v __attribute__((ext_vector_type(4)));
typedef uint16_t u16x8v __attribute__((ext_vector_type(8)));
typedef float f32x4 __attribute__((ext_vector_type(4)));

#define DEV static __device__ __forceinline__

DEV u16_t f2bf(float f) {
  u32_t u = __float_as_uint(f);
  u += 0x7fffu + ((u >> 16) & 1u);   // round-to-nearest-even
  return (u16_t)(u >> 16);
}
DEV float sig_(float x) { return 1.f / (1.f + __expf(-x)); }
DEV float th_(float x) {
  x = fminf(15.f, fmaxf(-15.f, x));
  float e = __expf(2.f * x);
  return (e - 1.f) / (e + 1.f);
}

// =================== setup kernels ===================

// Permuted+concatenated bf16 weights: dest row p = g*64 + q*16 + j
// <- original gate row q*HH + (p>>6)*16 + (p&15); row content = [wih | whh].
__global__ void k_buildWC(const float* __restrict__ wih, const float* __restrict__ whh,
                          const float* __restrict__ bih, const float* __restrict__ bhh,
                          u16_t* __restrict__ WC, float* __restrict__ bs, int HH)
{
  const int K = HH * 2;
  const int nk8 = K >> 3;
  const long total = (long)HH * 4 * nk8;
  long idx = (long)blockIdx.x * blockDim.x + threadIdx.x;
  if (idx >= total) return;
  int p = (int)(idx / nk8);
  int k = (int)(idx - (long)p * nk8) << 3;
  int q = (p >> 4) & 3;
  int orig = q * HH + ((p >> 6) << 4) + (p & 15);
  const float* s = (k < HH) ? (wih + (size_t)orig * HH + k)
                            : (whh + (size_t)orig * HH + (k - HH));
  f32x4 a = *(const f32x4*)s;
  f32x4 b = *(const f32x4*)(s + 4);
  u16x8v o;
  o[0]=f2bf(a[0]); o[1]=f2bf(a[1]); o[2]=f2bf(a[2]); o[3]=f2bf(a[3]);
  o[4]=f2bf(b[0]); o[5]=f2bf(b[1]); o[6]=f2bf(b[2]); o[7]=f2bf(b[3]);
  *(u16x8v*)(WC + (size_t)p * K + k) = o;
  if (k == 0) bs[p] = bih[orig] + bhh[orig];
}

// init slab 0 of XIN/H1/H2 (bf16)
__global__ void k_init(const float* __restrict__ h0f, const float* __restrict__ h0b,
                       const float* __restrict__ h01, const float* __restrict__ h02,
                       u16_t* __restrict__ XIN0, u16_t* __restrict__ H1i, u16_t* __restrict__ H2i)
{
  int i = blockIdx.x * 256 + threadIdx.x;
  if (i >= 64 * 1024) return;
  int b = i >> 10, d = i & 1023;
  XIN0[i] = f2bf(d < 512 ? h0f[b * 512 + d] : h0b[b * 512 + (d - 512)]);
  H1i[i] = f2bf(h01[i]);
  H2i[i] = f2bf(h02[i]);
}

// embedding gather, faithful .view(S,B,H) remap + padding_idx=0
__global__ void k_emb(const int* __restrict__ x, const float* __restrict__ emb,
                      u16_t* __restrict__ Xemb)
{
  int idx = blockIdx.x * 256 + threadIdx.x;
  if (idx >= 524288) return;
  int sb = idx >> 6;
  int h0 = (idx & 63) << 3;
  int token = x[(sb >> 7) * 128 + (sb & 127)];
  u16x8v o = {0,0,0,0,0,0,0,0};
  if (token != 0) {
    const float* e = emb + (size_t)token * 512 + h0;
    f32x4 a = *(const f32x4*)e;
    f32x4 b = *(const f32x4*)(e + 4);
    o[0]=f2bf(a[0]); o[1]=f2bf(a[1]); o[2]=f2bf(a[2]); o[3]=f2bf(a[3]);
    o[4]=f2bf(b[0]); o[5]=f2bf(b[1]); o[6]=f2bf(b[2]); o[7]=f2bf(b[3]);
  }
  *(u16x8v*)(Xemb + (size_t)sb * 512 + h0) = o;
}

// =================== GEMM helpers ===================
// Stage A chunk [64 x 512 bf16] into LDS with XOR swizzle (G4: kills the
// stride-1024B 16-way bank conflict on ds_read_b128).
DEV void stage_chunk(u16_t* smem, const u16_t* src, int ld, int wave, int lane)
{
#pragma unroll
  for (int j = 0; j < 16; ++j) {
    int r = j * 4 + wave;
    s16x8 v = *(const s16x8*)(src + (size_t)r * ld + lane * 8);
    *(s16x8*)((char*)smem + r * 1024 + ((lane * 16) ^ ((r & 7) << 4))) = v;
  }
}

DEV s16x8 ld_afrag(const u16_t* smem, int m, int s, int lane)
{
  int r = m * 16 + (lane & 15);
  int off = (s * 64 + ((lane >> 4) << 4)) ^ ((r & 7) << 4);
  return *(const s16x8*)((const char*)smem + r * 1024 + off);
}

// one 512-K chunk via LDS staging, register-resident weights (off critical path)
DEV void chunk_reg(u16_t* smem, f32x4 acc[4], const u16_t* a, int ld,
                   const s16x8 wr[16], int wave, int lane)
{
  __syncthreads();
  stage_chunk(smem, a, ld, wave, lane);
  __syncthreads();
#pragma unroll
  for (int s = 0; s < 16; ++s) {
#pragma unroll
    for (int m = 0; m < 4; ++m) {
      s16x8 af = ld_afrag(smem, m, s, lane);
      acc[m] = __builtin_amdgcn_mfma_f32_16x16x32_bf16(af, wr[s], acc[m], 0, 0, 0);
    }
  }
}

// one 512-K chunk, DIRECT global->MFMA A-fragments (critical path: no LDS,
// no barriers; 4x wave redundancy absorbed by local L2)
DEV void dchunk(f32x4 acc[4], const u16_t* a, int ld, const s16x8 wr[16], int lane)
{
#pragma unroll
  for (int s = 0; s < 16; ++s) {
#pragma unroll
    for (int m = 0; m < 4; ++m) {
      s16x8 af = *(const s16x8*)(a + (size_t)(m * 16 + (lane & 15)) * ld
                                 + s * 32 + ((lane >> 4) << 3));
      acc[m] = __builtin_amdgcn_mfma_f32_16x16x32_bf16(af, wr[s], acc[m], 0, 0, 0);
    }
  }
}

// wave's [64 x 16] tile -> smem exchange ex[wave][row][col]
DEV void acc_to_ex(float* ex, const f32x4 acc[4], int wave, int lane)
{
#pragma unroll
  for (int m = 0; m < 4; ++m)
#pragma unroll
    for (int r = 0; r < 4; ++r)
      ex[wave * 1024 + (m * 16 + ((lane >> 4) << 2) + r) * 16 + (lane & 15)] = acc[m][r];
}

// =================== fenceless flag sync ===================
// Data published with relaxed agent-scope atomic stores (commit at the
// coherence point / L3). __syncthreads drains vmcnt before the flag store.
// NO agent fences anywhere -> no L2 invalidates.
DEV void ast8(void* p, const void* v)
{
  unsigned long long u; __builtin_memcpy(&u, v, 8);
  __hip_atomic_store((unsigned long long*)p, u, __ATOMIC_RELAXED, __HIP_MEMORY_SCOPE_AGENT);
}

DEV void wait_flags(u32_t* f, int n, int tid)
{
  if (tid < 64) {
    int guard = 0;
    for (;;) {
      u32_t v = (tid < n) ? __hip_atomic_load(f + tid, __ATOMIC_RELAXED, __HIP_MEMORY_SCOPE_AGENT) : 1u;
      if (__all(v != 0)) break;
      if (++guard > (1 << 24)) break;   // safety: never hang forever
    }
  }
  __builtin_amdgcn_fence(__ATOMIC_ACQUIRE, "workgroup");  // compiler ordering only
  __syncthreads();
}

DEV void set_flag(u32_t* f, int tid)
{
  __syncthreads();   // s_waitcnt vmcnt(0) for every wave before s_barrier
  if (tid == 0) {
    __builtin_amdgcn_fence(__ATOMIC_RELEASE, "workgroup");  // compiler ordering only
    __hip_atomic_store(f, 1u, __ATOMIC_RELAXED, __HIP_MEMORY_SCOPE_AGENT);
  }
}

// =================== persistent RNN kernel ===================
// 192 WGs, 1/CU: wg 0..63 cells (fwd 0..31, bwd 32..63), 64..127 layer1,
// 128..191 layer2. All cross-WG buffers are per-step fresh slabs.
// ALL weights register-resident (stacked: 256 VGPR, cells: 128 VGPR).
struct RP {
  const u16_t *WCf, *WCb, *WC1, *WC2;
  const float *bsf, *bsb, *bs1, *bs2;
  const u16_t *Xemb;
  u16_t *XIN, *H1, *H2;     // [129][64][1024] bf16 slabs
  float *C2;                // [129][64][1024] f32 slabs (slab u+1 = c2 after step u)
  u32_t *FLC, *FLA, *FLB;   // [128][64]
  const float *c0f, *c0b, *c02;
};

__global__ __launch_bounds__(256, 1) void k_rnn(RP P)
{
  __shared__ u16_t smem[32768];  // 64 KB staging, reused as f32 exchange
  const int tid = threadIdx.x;
  const int wave = tid >> 6, lane = tid & 63;
  const int wg = blockIdx.x;
  const int ab = tid >> 2, aj0 = (tid & 3) << 2;
  const f32x4 vzero = {0.f, 0.f, 0.f, 0.f};

  if (wg < 64) {
    // ---------------- fwd/bwd cells ----------------
    const int g = wg;
    const bool cfwd = g < 32;
    const int ccg = cfwd ? g : g - 32;
    const u16_t* WCc = cfwd ? P.WCf : P.WCb;
    const float* bsc = cfwd ? P.bsf : P.bsb;
    const float* c0 = cfwd ? P.c0f : P.c0b;
    float c_cell[4];
#pragma unroll
    for (int i = 0; i < 4; ++i) c_cell[i] = c0[ab * 512 + ccg * 16 + aj0 + i];
    const u16_t* wrow = WCc + (size_t)(ccg * 64 + wave * 16 + (lane & 15)) * 1024
                        + ((lane >> 4) << 3);
    s16x8 wE[16], wL[16];          // all weights in registers
#pragma unroll
    for (int s = 0; s < 16; ++s) {
      wE[s] = *(const s16x8*)(wrow + s * 32);
      wL[s] = *(const s16x8*)(wrow + 512 + s * 32);
    }

    for (int t = 0; t < 128; ++t) {
      f32x4 acc[4] = {vzero, vzero, vzero, vzero};
      int trow = cfwd ? t : 127 - t;
      // early: embedding chunk (always available), LDS-staged
      chunk_reg(smem, acc, P.Xemb + (size_t)trow * 32768, 512, wE, wave, lane);
      // late: own h(t-1), direct-loaded (only own 32-group needed)
      if (t > 0) wait_flags(P.FLC + (t - 1) * 64 + (cfwd ? 0 : 32), 32, tid);
      dchunk(acc, P.XIN + (size_t)t * 65536 + (cfwd ? 0 : 512), 1024, wL, lane);
      __syncthreads();
      float* ex = (float*)smem;
      acc_to_ex(ex, acc, wave, lane);
      __syncthreads();
      u16x4v hv;
#pragma unroll
      for (int i = 0; i < 4; ++i) {
        int j = aj0 + i;
        float gi = ex[0    + ab * 16 + j] + bsc[ccg * 64 + j];
        float gf = ex[1024 + ab * 16 + j] + bsc[ccg * 64 + 16 + j];
        float gg = ex[2048 + ab * 16 + j] + bsc[ccg * 64 + 32 + j];
        float go = ex[3072 + ab * 16 + j] + bsc[ccg * 64 + 48 + j];
        float c = sig_(gf) * c_cell[i] + sig_(gi) * th_(gg);
        c_cell[i] = c;
        hv[i] = f2bf(sig_(go) * th_(c));
      }
      ast8(P.XIN + (size_t)(t + 1) * 65536 + ab * 1024 + (cfwd ? 0 : 512) + ccg * 16 + aj0, &hv);
      set_flag(P.FLC + t * 64 + g, tid);
    }
  } else if (wg < 128) {
    // ---------------- stacked layer 1 ----------------
    const int g = wg - 64;
    const u16_t* wrow = P.WC1 + (size_t)(g * 64 + wave * 16 + (lane & 15)) * 2048
                        + ((lane >> 4) << 3);
    s16x8 wE[32], wL[32];          // all 2048-K weights in registers (256 VGPR)
#pragma unroll
    for (int s = 0; s < 32; ++s) {
      wE[s] = *(const s16x8*)(wrow + s * 32);           // xin side K 0..1023
      wL[s] = *(const s16x8*)(wrow + 1024 + s * 32);    // h1-prev side K 1024..2047
    }
    for (int u = 0; u < 128; ++u) {
      f32x4 acc[4] = {vzero, vzero, vzero, vzero};
      // early: xin_u (cells run ahead -> near-zero wait), LDS-staged
      wait_flags(P.FLC + u * 64, 64, tid);
      const u16_t* xin = P.XIN + (size_t)(u + 1) * 65536;
      chunk_reg(smem, acc, xin, 1024, wE, wave, lane);
      chunk_reg(smem, acc, xin + 512, 1024, wE + 16, wave, lane);
      // late: h1(u-1) + c2(u) -- single-flag wait (implies all FLA[u-1])
      if (u > 0) wait_flags(P.FLB + (u - 1) * 64 + g, 1, tid);
      const u16_t* h1p = P.H1 + (size_t)u * 65536;
      dchunk(acc, h1p, 1024, wL, lane);
      dchunk(acc, h1p + 512, 1024, wL + 16, lane);
      __syncthreads();
      float* ex = (float*)smem;
      acc_to_ex(ex, acc, wave, lane);
      __syncthreads();
      const float* c2p = (u == 0) ? (P.c02 + ab * 1024 + g * 16 + aj0)
                                  : (P.C2 + (size_t)u * 65536 + ab * 1024 + g * 16 + aj0);
      u16x4v hv;
#pragma unroll
      for (int i = 0; i < 4; ++i) {
        int j = aj0 + i;
        float gq[4];
#pragma unroll
        for (int q = 0; q < 4; ++q)
          gq[q] = ex[q * 1024 + ab * 16 + j] + P.bs1[g * 64 + q * 16 + j];
        // faithful quirk: layer-1 cell consumes c2; its own c is discarded
        float c1 = sig_(gq[1]) * c2p[i] + sig_(gq[0]) * th_(gq[2]);
        hv[i] = f2bf(sig_(gq[3]) * th_(c1));
      }
      ast8(P.H1 + (size_t)(u + 1) * 65536 + ab * 1024 + g * 16 + aj0, &hv);
      set_flag(P.FLA + u * 64 + g, tid);
    }
  } else {
    // ---------------- stacked layer 2 ----------------
    const int g = wg - 128;
    const u16_t* wrow = P.WC2 + (size_t)(g * 64 + wave * 16 + (lane & 15)) * 2048
                        + ((lane >> 4) << 3);
    s16x8 wE[32], wL[32];
#pragma unroll
    for (int s = 0; s < 32; ++s) {
      wE[s] = *(const s16x8*)(wrow + 1024 + s * 32);    // h2-prev side K 1024..2047
      wL[s] = *(const s16x8*)(wrow + s * 32);           // h1n side K 0..1023
    }
    float c2r[4];
#pragma unroll
    for (int i = 0; i < 4; ++i) c2r[i] = P.c02[ab * 1024 + g * 16 + aj0 + i];

    for (int u = 0; u < 128; ++u) {
      f32x4 acc[4] = {vzero, vzero, vzero, vzero};
      // early: h2(u-1), LDS-staged
      if (u > 0) wait_flags(P.FLB + (u - 1) * 64, 64, tid);
      const u16_t* h2p = P.H2 + (size_t)u * 65536;
      chunk_reg(smem, acc, h2p, 1024, wE, wave, lane);
      chunk_reg(smem, acc, h2p + 512, 1024, wE + 16, wave, lane);
      // late: h1n (critical hop), direct-loaded
      wait_flags(P.FLA + u * 64, 64, tid);
      const u16_t* h1n = P.H1 + (size_t)(u + 1) * 65536;
      dchunk(acc, h1n, 1024, wL, lane);
      dchunk(acc, h1n + 512, 1024, wL + 16, lane);
      __syncthreads();
      float* ex = (float*)smem;
      acc_to_ex(ex, acc, wave, lane);
      __syncthreads();
      u16x4v hv; float c2o[4];
#pragma unroll
      for (int i = 0; i < 4; ++i) {
        int j = aj0 + i;
        float gq[4];
#pragma unroll
        for (int q = 0; q < 4; ++q)
          gq[q] = ex[q * 1024 + ab * 16 + j] + P.bs2[g * 64 + q * 16 + j];
        float c2n = sig_(gq[1]) * c2r[i] + sig_(gq[0]) * th_(gq[2]);
        c2r[i] = c2n; c2o[i] = c2n;
        hv[i] = f2bf(sig_(gq[3]) * th_(c2n));
      }
      ast8(P.H2 + (size_t)(u + 1) * 65536 + ab * 1024 + g * 16 + aj0, &hv);
      float* c2dst = P.C2 + (size_t)(u + 1) * 65536 + ab * 1024 + g * 16 + aj0;
      ast8(c2dst, &c2o[0]);
      ast8(c2dst + 2, &c2o[2]);
      set_flag(P.FLB + u * 64 + g, tid);
    }
  }
}

// =================== final linear ===================
__global__ __launch_bounds__(256, 1) void k_logits(const u16_t* __restrict__ h2,
                                                   const float* __restrict__ wlin,
                                                   const float* __restrict__ blin,
                                                   float* __restrict__ out)
{
  __shared__ u16_t smem[32768];
  const int tid = threadIdx.x, wave = tid >> 6, lane = tid & 63;
  const int n0 = blockIdx.x * 128 + wave * 32;
  const f32x4 vzero = {0.f, 0.f, 0.f, 0.f};
  f32x4 acc[2][4];
#pragma unroll
  for (int nt = 0; nt < 2; ++nt)
#pragma unroll
    for (int m = 0; m < 4; ++m) acc[nt][m] = vzero;

  for (int c = 0; c < 2; ++c) {
    __syncthreads();
    stage_chunk(smem, h2 + c * 512, 1024, wave, lane);
    __syncthreads();
#pragma unroll
    for (int s = 0; s < 16; ++s) {
#pragma unroll
      for (int nt = 0; nt < 2; ++nt) {
        const float* wp = wlin + (size_t)(n0 + nt * 16 + (lane & 15)) * 1024
                          + c * 512 + s * 32 + ((lane >> 4) << 3);
        f32x4 w0 = *(const f32x4*)wp;
        f32x4 w1 = *(const f32x4*)(wp + 4);
        s16x8 bf;
        bf[0]=(short)f2bf(w0[0]); bf[1]=(short)f2bf(w0[1]);
        bf[2]=(short)f2bf(w0[2]); bf[3]=(short)f2bf(w0[3]);
        bf[4]=(short)f2bf(w1[0]); bf[5]=(short)f2bf(w1[1]);
        bf[6]=(short)f2bf(w1[2]); bf[7]=(short)f2bf(w1[3]);
#pragma unroll
        for (int m = 0; m < 4; ++m) {
          s16x8 af = ld_afrag(smem, m, s, lane);
          acc[nt][m] = __builtin_amdgcn_mfma_f32_16x16x32_bf16(af, bf, acc[nt][m], 0, 0, 0);
        }
      }
    }
  }
#pragma unroll
  for (int nt = 0; nt < 2; ++nt) {
    int col = n0 + nt * 16 + (lane & 15);
    float bl = blin[col];
#pragma unroll
    for (int m = 0; m < 4; ++m)
#pragma unroll
      for (int r = 0; r < 4; ++r) {
        int row = m * 16 + ((lane >> 4) << 2) + r;
        out[(size_t)row * 32000 + col] = acc[nt][m][r] + bl;
      }
  }
}

// =================== host ===================
extern "C" void kernel_launch(void* const* d_in, const int* in_sizes, int n_in,
                              void* d_out, int out_size, void* d_ws, size_t ws_size,
                              hipStream_t stream)
{
  (void)in_sizes; (void)n_in; (void)out_size;
  const int*   x     = (const int*)d_in[0];
  const float* emb   = (const float*)d_in[1];
  const float* h0f   = (const float*)d_in[2];
  const float* c0f   = (const float*)d_in[3];
  const float* h0b   = (const float*)d_in[4];
  const float* c0b   = (const float*)d_in[5];
  const float* h01   = (const float*)d_in[6];
  const float* h02   = (const float*)d_in[7];
  const float* c02   = (const float*)d_in[8];
  const float* wih_f = (const float*)d_in[9];
  const float* whh_f = (const float*)d_in[10];
  const float* bih_f = (const float*)d_in[11];
  const float* bhh_f = (const float*)d_in[12];
  const float* wih_b = (const float*)d_in[13];
  const float* whh_b = (const float*)d_in[14];
  const float* bih_b = (const float*)d_in[15];
  const float* bhh_b = (const float*)d_in[16];
  const float* wih1  = (const float*)d_in[17];
  const float* whh1  = (const float*)d_in[18];
  const float* bih1  = (const float*)d_in[19];
  const float* bhh1  = (const float*)d_in[20];
  const float* wih2  = (const float*)d_in[21];
  const float* whh2  = (const float*)d_in[22];
  const float* bih2  = (const float*)d_in[23];
  const float* bhh2  = (const float*)d_in[24];
  const float* wlin  = (const float*)d_in[25];
  const float* blin  = (const float*)d_in[26];

  char* ws = (char*)d_ws;
  size_t off = 0;
  auto take = [&](size_t n) { char* p = ws + off; off += (n + 255) & ~(size_t)255; return p; };

  u16_t* WCf  = (u16_t*)take(2048UL * 1024 * 2);
  u16_t* WCb  = (u16_t*)take(2048UL * 1024 * 2);
  u16_t* WC1  = (u16_t*)take(4096UL * 2048 * 2);
  u16_t* WC2  = (u16_t*)take(4096UL * 2048 * 2);
  float* bsf  = (float*)take(2048UL * 4);
  float* bsb  = (float*)take(2048UL * 4);
  float* bs1  = (float*)take(4096UL * 4);
  float* bs2  = (float*)take(4096UL * 4);
  u16_t* Xemb = (u16_t*)take(8192UL * 512 * 2);
  u16_t* XIN  = (u16_t*)take(129UL * 65536 * 2);
  u16_t* H1   = (u16_t*)take(129UL * 65536 * 2);
  u16_t* H2   = (u16_t*)take(129UL * 65536 * 2);
  float* C2   = (float*)take(129UL * 65536 * 4);
  char* flagbase = ws + off;
  u32_t* FLC  = (u32_t*)take(128UL * 64 * 4);
  u32_t* FLA  = (u32_t*)take(128UL * 64 * 4);
  u32_t* FLB  = (u32_t*)take(128UL * 64 * 4);
  size_t flagbytes = (size_t)((ws + off) - flagbase);

  if (off > ws_size) return;  // workspace too small: fail loudly via wrong output

  hipMemsetAsync(flagbase, 0, flagbytes, stream);

  k_buildWC<<<1024, 256, 0, stream>>>(wih_f, whh_f, bih_f, bhh_f, WCf, bsf, 512);
  k_buildWC<<<1024, 256, 0, stream>>>(wih_b, whh_b, bih_b, bhh_b, WCb, bsb, 512);
  k_buildWC<<<4096, 256, 0, stream>>>(wih1, whh1, bih1, bhh1, WC1, bs1, 1024);
  k_buildWC<<<4096, 256, 0, stream>>>(wih2, whh2, bih2, bhh2, WC2, bs2, 1024);
  k_init<<<256, 256, 0, stream>>>(h0f, h0b, h01, h02, XIN, H1, H2);
  k_emb<<<2048, 256, 0, stream>>>(x, emb, Xemb);

  RP P;
  P.WCf = WCf; P.WCb = WCb; P.WC1 = WC1; P.WC2 = WC2;
  P.bsf = bsf; P.bsb = bsb; P.bs1 = bs1; P.bs2 = bs2;
  P.Xemb = Xemb; P.XIN = XIN; P.H1 = H1; P.H2 = H2; P.C2 = C2;
  P.FLC = FLC; P.FLA = FLA; P.FLB = FLB;
  P.c0f = c0f; P.c0b = c0b; P.c02 = c02;
  k_rnn<<<192, 256, 0, stream>>>(P);

  k_logits<<<250, 256, 0, stream>>>(H2 + 128UL * 65536, wlin, blin, (float*)d_out);
}

// Round 4
// 2463.489 us; speedup vs baseline: 2.5346x; 2.5346x over previous
//
#include <hip/hip_runtime.h>
#include <stdint.h>
#include <stddef.h>

typedef uint16_t u16_t;
typedef uint32_t u32_t;
typedef short s16x8 __attribute__((ext_vector_type(8)));
typedef uint16_t u16x4v __attribute__((ext_vector_type(4)));
typedef uint16_t u16x8v __attribute__((ext_vector_type(8)));
typedef float f32x4 __attribute__((ext_vector_type(4)));

#define DEV static __device__ __forceinline__

DEV u16_t f2bf(float f) {
  u32_t u = __float_as_uint(f);
  u += 0x7fffu + ((u >> 16) & 1u);   // round-to-nearest-even
  return (u16_t)(u >> 16);
}
DEV float sig_(float x) { return 1.f / (1.f + __expf(-x)); }
DEV float th_(float x) {
  x = fminf(15.f, fmaxf(-15.f, x));
  float e = __expf(2.f * x);
  return (e - 1.f) / (e + 1.f);
}

// =================== setup kernels ===================

// Permuted+concatenated bf16 weights: dest row p = g*64 + q*16 + j
// <- original gate row q*HH + (p>>6)*16 + (p&15); row content = [wih | whh].
__global__ void k_buildWC(const float* __restrict__ wih, const float* __restrict__ whh,
                          const float* __restrict__ bih, const float* __restrict__ bhh,
                          u16_t* __restrict__ WC, float* __restrict__ bs, int HH)
{
  const int K = HH * 2;
  const int nk8 = K >> 3;
  const long total = (long)HH * 4 * nk8;
  long idx = (long)blockIdx.x * blockDim.x + threadIdx.x;
  if (idx >= total) return;
  int p = (int)(idx / nk8);
  int k = (int)(idx - (long)p * nk8) << 3;
  int q = (p >> 4) & 3;
  int orig = q * HH + ((p >> 6) << 4) + (p & 15);
  const float* s = (k < HH) ? (wih + (size_t)orig * HH + k)
                            : (whh + (size_t)orig * HH + (k - HH));
  f32x4 a = *(const f32x4*)s;
  f32x4 b = *(const f32x4*)(s + 4);
  u16x8v o;
  o[0]=f2bf(a[0]); o[1]=f2bf(a[1]); o[2]=f2bf(a[2]); o[3]=f2bf(a[3]);
  o[4]=f2bf(b[0]); o[5]=f2bf(b[1]); o[6]=f2bf(b[2]); o[7]=f2bf(b[3]);
  *(u16x8v*)(WC + (size_t)p * K + k) = o;
  if (k == 0) bs[p] = bih[orig] + bhh[orig];
}

// init slab 0 of XIN/H1/H2 (bf16)
__global__ void k_init(const float* __restrict__ h0f, const float* __restrict__ h0b,
                       const float* __restrict__ h01, const float* __restrict__ h02,
                       u16_t* __restrict__ XIN0, u16_t* __restrict__ H1i, u16_t* __restrict__ H2i)
{
  int i = blockIdx.x * 256 + threadIdx.x;
  if (i >= 64 * 1024) return;
  int b = i >> 10, d = i & 1023;
  XIN0[i] = f2bf(d < 512 ? h0f[b * 512 + d] : h0b[b * 512 + (d - 512)]);
  H1i[i] = f2bf(h01[i]);
  H2i[i] = f2bf(h02[i]);
}

// embedding gather, faithful .view(S,B,H) remap + padding_idx=0
__global__ void k_emb(const int* __restrict__ x, const float* __restrict__ emb,
                      u16_t* __restrict__ Xemb)
{
  int idx = blockIdx.x * 256 + threadIdx.x;
  if (idx >= 524288) return;
  int sb = idx >> 6;
  int h0 = (idx & 63) << 3;
  int token = x[(sb >> 7) * 128 + (sb & 127)];
  u16x8v o = {0,0,0,0,0,0,0,0};
  if (token != 0) {
    const float* e = emb + (size_t)token * 512 + h0;
    f32x4 a = *(const f32x4*)e;
    f32x4 b = *(const f32x4*)(e + 4);
    o[0]=f2bf(a[0]); o[1]=f2bf(a[1]); o[2]=f2bf(a[2]); o[3]=f2bf(a[3]);
    o[4]=f2bf(b[0]); o[5]=f2bf(b[1]); o[6]=f2bf(b[2]); o[7]=f2bf(b[3]);
  }
  *(u16x8v*)(Xemb + (size_t)sb * 512 + h0) = o;
}

// =================== GEMM helpers ===================
// Stage A chunk [64 x 512 bf16] into LDS with XOR swizzle (G4: kills the
// stride-1024B 16-way bank conflict on ds_read_b128). W = waves per WG.
template<int W>
DEV void stage_chunkT(u16_t* smem, const u16_t* src, int ld, int wave, int lane)
{
#pragma unroll
  for (int j = 0; j < 64 / W; ++j) {
    int r = j * W + wave;
    s16x8 v = *(const s16x8*)(src + (size_t)r * ld + lane * 8);
    *(s16x8*)((char*)smem + r * 1024 + ((lane * 16) ^ ((r & 7) << 4))) = v;
  }
}

DEV s16x8 ld_afrag(const u16_t* smem, int m, int s, int lane)
{
  int r = m * 16 + (lane & 15);
  int off = (s * 64 + ((lane >> 4) << 4)) ^ ((r & 7) << 4);
  return *(const s16x8*)((const char*)smem + r * 1024 + off);
}

// one 512-K chunk, streamed (L2-resident) weights
DEV void chunk_stream(u16_t* smem, f32x4 acc[4], const u16_t* a, int ld,
                      const u16_t* wptr, int wave, int lane)
{
  __syncthreads();
  stage_chunkT<8>(smem, a, ld, wave, lane);
  __syncthreads();
#pragma unroll
  for (int s = 0; s < 16; ++s) {
    s16x8 bf = *(const s16x8*)(wptr + s * 32);
#pragma unroll
    for (int m = 0; m < 4; ++m) {
      s16x8 af = ld_afrag(smem, m, s, lane);
      acc[m] = __builtin_amdgcn_mfma_f32_16x16x32_bf16(af, bf, acc[m], 0, 0, 0);
    }
  }
}

// one 512-K chunk, register-resident weights
DEV void chunk_reg(u16_t* smem, f32x4 acc[4], const u16_t* a, int ld,
                   const s16x8 wr[16], int wave, int lane)
{
  __syncthreads();
  stage_chunkT<8>(smem, a, ld, wave, lane);
  __syncthreads();
#pragma unroll
  for (int s = 0; s < 16; ++s) {
#pragma unroll
    for (int m = 0; m < 4; ++m) {
      s16x8 af = ld_afrag(smem, m, s, lane);
      acc[m] = __builtin_amdgcn_mfma_f32_16x16x32_bf16(af, wr[s], acc[m], 0, 0, 0);
    }
  }
}

// wave's [64 x 16] tile -> smem exchange ex[wave][row][col]
DEV void acc_to_ex(float* ex, const f32x4 acc[4], int wave, int lane)
{
#pragma unroll
  for (int m = 0; m < 4; ++m)
#pragma unroll
    for (int r = 0; r < 4; ++r)
      ex[wave * 1024 + (m * 16 + ((lane >> 4) << 2) + r) * 16 + (lane & 15)] = acc[m][r];
}

// =================== fenceless flag sync ===================
// Data published with relaxed agent-scope atomic stores (commit at the
// coherence point / L3). __syncthreads drains vmcnt before the flag store.
// NO agent fences anywhere -> no L2 invalidates, weights stay L2-resident.
DEV void ast8(void* p, const void* v)
{
  unsigned long long u; __builtin_memcpy(&u, v, 8);
  __hip_atomic_store((unsigned long long*)p, u, __ATOMIC_RELAXED, __HIP_MEMORY_SCOPE_AGENT);
}

DEV void wait_flags(u32_t* f, int n, int tid)
{
  if (tid < 64) {
    int guard = 0;
    for (;;) {
      u32_t v = (tid < n) ? __hip_atomic_load(f + tid, __ATOMIC_RELAXED, __HIP_MEMORY_SCOPE_AGENT) : 1u;
      if (__all(v != 0)) break;
      if (++guard > (1 << 22)) break;   // safety: never hang forever
      __builtin_amdgcn_s_sleep(1);      // throttle poll traffic off the fabric
    }
  }
  __builtin_amdgcn_fence(__ATOMIC_ACQUIRE, "workgroup");  // compiler ordering only
  __syncthreads();
}

DEV void set_flag(u32_t* f, int tid)
{
  __syncthreads();   // s_waitcnt vmcnt(0) for every wave before s_barrier
  if (tid == 0) {
    __builtin_amdgcn_fence(__ATOMIC_RELEASE, "workgroup");  // compiler ordering only
    __hip_atomic_store(f, 1u, __ATOMIC_RELAXED, __HIP_MEMORY_SCOPE_AGENT);
  }
}

// =================== persistent RNN kernel ===================
// 96 WGs x 512 threads (8 waves): wg 0..31 cells (fwd 0..15, bwd 16..31),
// 32..63 layer1 (G=wg-32), 64..95 layer2 (G=wg-64). Each WG owns 128 gate
// cols = 32 h-dims. All cross-WG buffers are per-step fresh slabs.
struct RP {
  const u16_t *WCf, *WCb, *WC1, *WC2;
  const float *bsf, *bsb, *bs1, *bs2;
  const u16_t *Xemb;
  u16_t *XIN, *H1, *H2;     // [129][64][1024] bf16 slabs
  float *C2;                // [129][64][1024] f32 slabs (slab u+1 = c2 after step u)
  u32_t *FLC, *FLA, *FLB;   // [128][32]
  const float *c0f, *c0b, *c02;
};

__global__ __launch_bounds__(512, 2) void k_rnn(RP P)
{
  __shared__ u16_t smem[32768];  // 64 KB staging, reused as f32 exchange [8][64][16]
  const int tid = threadIdx.x;
  const int wave = tid >> 6, lane = tid & 63;
  const int wg = blockIdx.x;
  // activation thread map: 4 outputs per thread
  const int b  = tid >> 3;          // batch 0..63
  const int d0 = (tid & 7) << 2;    // local h-dim base 0..28
  const int gl = d0 >> 4;           // 16-block within the 32 dims
  const int jj = d0 & 15;
  const f32x4 vzero = {0.f, 0.f, 0.f, 0.f};

  if (wg < 32) {
    // ---------------- fwd/bwd cells ----------------
    const bool cfwd = wg < 16;
    const int G = cfwd ? wg : wg - 16;          // 0..15 within direction
    const u16_t* WCc = cfwd ? P.WCf : P.WCb;
    const float* bsc = cfwd ? P.bsf : P.bsb;
    const float* c0 = cfwd ? P.c0f : P.c0b;
    float c_cell[4];
#pragma unroll
    for (int i = 0; i < 4; ++i) c_cell[i] = c0[b * 512 + G * 32 + d0 + i];
    const u16_t* wrow = WCc + (size_t)(G * 128 + wave * 16 + (lane & 15)) * 1024
                        + ((lane >> 4) << 3);
    s16x8 wL[16];                   // late half K 512..1023 (own-h side) in regs
#pragma unroll
    for (int s = 0; s < 16; ++s) wL[s] = *(const s16x8*)(wrow + 512 + s * 32);

    for (int t = 0; t < 128; ++t) {
      f32x4 acc[4] = {vzero, vzero, vzero, vzero};
      int trow = cfwd ? t : 127 - t;
      // early: embedding chunk (always available), streamed weights
      chunk_stream(smem, acc, P.Xemb + (size_t)trow * 32768, 512, wrow, wave, lane);
      // late: own-direction h(t-1)
      if (t > 0) wait_flags(P.FLC + (t - 1) * 32 + (cfwd ? 0 : 16), 16, tid);
      chunk_reg(smem, acc, P.XIN + (size_t)t * 65536 + (cfwd ? 0 : 512), 1024, wL, wave, lane);
      __syncthreads();
      float* ex = (float*)smem;
      acc_to_ex(ex, acc, wave, lane);
      __syncthreads();
      u16x4v hv;
#pragma unroll
      for (int i = 0; i < 4; ++i) {
        int j = jj + i;
        float gq[4];
#pragma unroll
        for (int q = 0; q < 4; ++q)
          gq[q] = ex[(gl * 4 + q) * 1024 + b * 16 + j] + bsc[G * 128 + gl * 64 + q * 16 + j];
        float c = sig_(gq[1]) * c_cell[i] + sig_(gq[0]) * th_(gq[2]);
        c_cell[i] = c;
        hv[i] = f2bf(sig_(gq[3]) * th_(c));
      }
      ast8(P.XIN + (size_t)(t + 1) * 65536 + b * 1024 + (cfwd ? 0 : 512) + G * 32 + d0, &hv);
      set_flag(P.FLC + t * 32 + wg, tid);
    }
  } else if (wg < 64) {
    // ---------------- stacked layer 1 ----------------
    const int G = wg - 32;
    const u16_t* wrow = P.WC1 + (size_t)(G * 128 + wave * 16 + (lane & 15)) * 2048
                        + ((lane >> 4) << 3);
    s16x8 wL[32];                   // late: h1-prev side K 1024..2047 in regs
#pragma unroll
    for (int s = 0; s < 32; ++s) wL[s] = *(const s16x8*)(wrow + 1024 + s * 32);

    for (int u = 0; u < 128; ++u) {
      f32x4 acc[4] = {vzero, vzero, vzero, vzero};
      // early: xin_u (cells run ahead), half-waits pipelined with chunks
      const u16_t* xin = P.XIN + (size_t)(u + 1) * 65536;
      wait_flags(P.FLC + u * 32, 16, tid);
      chunk_stream(smem, acc, xin, 1024, wrow, wave, lane);
      wait_flags(P.FLC + u * 32 + 16, 16, tid);
      chunk_stream(smem, acc, xin + 512, 1024, wrow + 512, wave, lane);
      // late: h1(u-1) + c2(u) -- single-flag wait (implies all FLA[u-1])
      if (u > 0) wait_flags(P.FLB + (u - 1) * 32 + G, 1, tid);
      const u16_t* h1p = P.H1 + (size_t)u * 65536;
      chunk_reg(smem, acc, h1p, 1024, wL, wave, lane);
      chunk_reg(smem, acc, h1p + 512, 1024, wL + 16, wave, lane);
      __syncthreads();
      float* ex = (float*)smem;
      acc_to_ex(ex, acc, wave, lane);
      __syncthreads();
      const float* c2p = (u == 0) ? (P.c02 + b * 1024 + G * 32 + d0)
                                  : (P.C2 + (size_t)u * 65536 + b * 1024 + G * 32 + d0);
      u16x4v hv;
#pragma unroll
      for (int i = 0; i < 4; ++i) {
        int j = jj + i;
        float gq[4];
#pragma unroll
        for (int q = 0; q < 4; ++q)
          gq[q] = ex[(gl * 4 + q) * 1024 + b * 16 + j] + P.bs1[G * 128 + gl * 64 + q * 16 + j];
        // faithful quirk: layer-1 cell consumes c2; its own c is discarded
        float c1 = sig_(gq[1]) * c2p[i] + sig_(gq[0]) * th_(gq[2]);
        hv[i] = f2bf(sig_(gq[3]) * th_(c1));
      }
      ast8(P.H1 + (size_t)(u + 1) * 65536 + b * 1024 + G * 32 + d0, &hv);
      set_flag(P.FLA + u * 32 + G, tid);
    }
  } else {
    // ---------------- stacked layer 2 ----------------
    const int G = wg - 64;
    const u16_t* wrow = P.WC2 + (size_t)(G * 128 + wave * 16 + (lane & 15)) * 2048
                        + ((lane >> 4) << 3);
    s16x8 wL[32];                   // late: h1n side K 0..1023 in regs
#pragma unroll
    for (int s = 0; s < 32; ++s) wL[s] = *(const s16x8*)(wrow + s * 32);
    float c2r[4];
#pragma unroll
    for (int i = 0; i < 4; ++i) c2r[i] = P.c02[b * 1024 + G * 32 + d0 + i];

    for (int u = 0; u < 128; ++u) {
      f32x4 acc[4] = {vzero, vzero, vzero, vzero};
      // early: h2(u-1), half-waits pipelined with chunks
      const u16_t* h2p = P.H2 + (size_t)u * 65536;
      if (u > 0) wait_flags(P.FLB + (u - 1) * 32, 16, tid);
      chunk_stream(smem, acc, h2p, 1024, wrow + 1024, wave, lane);
      if (u > 0) wait_flags(P.FLB + (u - 1) * 32 + 16, 16, tid);
      chunk_stream(smem, acc, h2p + 512, 1024, wrow + 1536, wave, lane);
      // late: h1n (critical hop), half-waits pipelined with chunks
      const u16_t* h1n = P.H1 + (size_t)(u + 1) * 65536;
      wait_flags(P.FLA + u * 32, 16, tid);
      chunk_reg(smem, acc, h1n, 1024, wL, wave, lane);
      wait_flags(P.FLA + u * 32 + 16, 16, tid);
      chunk_reg(smem, acc, h1n + 512, 1024, wL + 16, wave, lane);
      __syncthreads();
      float* ex = (float*)smem;
      acc_to_ex(ex, acc, wave, lane);
      __syncthreads();
      u16x4v hv; float c2o[4];
#pragma unroll
      for (int i = 0; i < 4; ++i) {
        int j = jj + i;
        float gq[4];
#pragma unroll
        for (int q = 0; q < 4; ++q)
          gq[q] = ex[(gl * 4 + q) * 1024 + b * 16 + j] + P.bs2[G * 128 + gl * 64 + q * 16 + j];
        float c2n = sig_(gq[1]) * c2r[i] + sig_(gq[0]) * th_(gq[2]);
        c2r[i] = c2n; c2o[i] = c2n;
        hv[i] = f2bf(sig_(gq[3]) * th_(c2n));
      }
      ast8(P.H2 + (size_t)(u + 1) * 65536 + b * 1024 + G * 32 + d0, &hv);
      float* c2dst = P.C2 + (size_t)(u + 1) * 65536 + b * 1024 + G * 32 + d0;
      ast8(c2dst, &c2o[0]);
      ast8(c2dst + 2, &c2o[2]);
      set_flag(P.FLB + u * 32 + G, tid);
    }
  }
}

// =================== final linear ===================
__global__ __launch_bounds__(256, 1) void k_logits(const u16_t* __restrict__ h2,
                                                   const float* __restrict__ wlin,
                                                   const float* __restrict__ blin,
                                                   float* __restrict__ out)
{
  __shared__ u16_t smem[32768];
  const int tid = threadIdx.x, wave = tid >> 6, lane = tid & 63;
  const int n0 = blockIdx.x * 128 + wave * 32;
  const f32x4 vzero = {0.f, 0.f, 0.f, 0.f};
  f32x4 acc[2][4];
#pragma unroll
  for (int nt = 0; nt < 2; ++nt)
#pragma unroll
    for (int m = 0; m < 4; ++m) acc[nt][m] = vzero;

  for (int c = 0; c < 2; ++c) {
    __syncthreads();
    stage_chunkT<4>(smem, h2 + c * 512, 1024, wave, lane);
    __syncthreads();
#pragma unroll
    for (int s = 0; s < 16; ++s) {
#pragma unroll
      for (int nt = 0; nt < 2; ++nt) {
        const float* wp = wlin + (size_t)(n0 + nt * 16 + (lane & 15)) * 1024
                          + c * 512 + s * 32 + ((lane >> 4) << 3);
        f32x4 w0 = *(const f32x4*)wp;
        f32x4 w1 = *(const f32x4*)(wp + 4);
        s16x8 bf;
        bf[0]=(short)f2bf(w0[0]); bf[1]=(short)f2bf(w0[1]);
        bf[2]=(short)f2bf(w0[2]); bf[3]=(short)f2bf(w0[3]);
        bf[4]=(short)f2bf(w1[0]); bf[5]=(short)f2bf(w1[1]);
        bf[6]=(short)f2bf(w1[2]); bf[7]=(short)f2bf(w1[3]);
#pragma unroll
        for (int m = 0; m < 4; ++m) {
          s16x8 af = ld_afrag(smem, m, s, lane);
          acc[nt][m] = __builtin_amdgcn_mfma_f32_16x16x32_bf16(af, bf, acc[nt][m], 0, 0, 0);
        }
      }
    }
  }
#pragma unroll
  for (int nt = 0; nt < 2; ++nt) {
    int col = n0 + nt * 16 + (lane & 15);
    float bl = blin[col];
#pragma unroll
    for (int m = 0; m < 4; ++m)
#pragma unroll
      for (int r = 0; r < 4; ++r) {
        int row = m * 16 + ((lane >> 4) << 2) + r;
        out[(size_t)row * 32000 + col] = acc[nt][m][r] + bl;
      }
  }
}

// =================== host ===================
extern "C" void kernel_launch(void* const* d_in, const int* in_sizes, int n_in,
                              void* d_out, int out_size, void* d_ws, size_t ws_size,
                              hipStream_t stream)
{
  (void)in_sizes; (void)n_in; (void)out_size;
  const int*   x     = (const int*)d_in[0];
  const float* emb   = (const float*)d_in[1];
  const float* h0f   = (const float*)d_in[2];
  const float* c0f   = (const float*)d_in[3];
  const float* h0b   = (const float*)d_in[4];
  const float* c0b   = (const float*)d_in[5];
  const float* h01   = (const float*)d_in[6];
  const float* h02   = (const float*)d_in[7];
  const float* c02   = (const float*)d_in[8];
  const float* wih_f = (const float*)d_in[9];
  const float* whh_f = (const float*)d_in[10];
  const float* bih_f = (const float*)d_in[11];
  const float* bhh_f = (const float*)d_in[12];
  const float* wih_b = (const float*)d_in[13];
  const float* whh_b = (const float*)d_in[14];
  const float* bih_b = (const float*)d_in[15];
  const float* bhh_b = (const float*)d_in[16];
  const float* wih1  = (const float*)d_in[17];
  const float* whh1  = (const float*)d_in[18];
  const float* bih1  = (const float*)d_in[19];
  const float* bhh1  = (const float*)d_in[20];
  const float* wih2  = (const float*)d_in[21];
  const float* whh2  = (const float*)d_in[22];
  const float* bih2  = (const float*)d_in[23];
  const float* bhh2  = (const float*)d_in[24];
  const float* wlin  = (const float*)d_in[25];
  const float* blin  = (const float*)d_in[26];

  char* ws = (char*)d_ws;
  size_t off = 0;
  auto take = [&](size_t n) { char* p = ws + off; off += (n + 255) & ~(size_t)255; return p; };

  u16_t* WCf  = (u16_t*)take(2048UL * 1024 * 2);
  u16_t* WCb  = (u16_t*)take(2048UL * 1024 * 2);
  u16_t* WC1  = (u16_t*)take(4096UL * 2048 * 2);
  u16_t* WC2  = (u16_t*)take(4096UL * 2048 * 2);
  float* bsf  = (float*)take(2048UL * 4);
  float* bsb  = (float*)take(2048UL * 4);
  float* bs1  = (float*)take(4096UL * 4);
  float* bs2  = (float*)take(4096UL * 4);
  u16_t* Xemb = (u16_t*)take(8192UL * 512 * 2);
  u16_t* XIN  = (u16_t*)take(129UL * 65536 * 2);
  u16_t* H1   = (u16_t*)take(129UL * 65536 * 2);
  u16_t* H2   = (u16_t*)take(129UL * 65536 * 2);
  float* C2   = (float*)take(129UL * 65536 * 4);
  char* flagbase = ws + off;
  u32_t* FLC  = (u32_t*)take(128UL * 32 * 4);
  u32_t* FLA  = (u32_t*)take(128UL * 32 * 4);
  u32_t* FLB  = (u32_t*)take(128UL * 32 * 4);
  size_t flagbytes = (size_t)((ws + off) - flagbase);

  if (off > ws_size) return;  // workspace too small: fail loudly via wrong output

  hipMemsetAsync(flagbase, 0, flagbytes, stream);

  k_buildWC<<<1024, 256, 0, stream>>>(wih_f, whh_f, bih_f, bhh_f, WCf, bsf, 512);
  k_buildWC<<<1024, 256, 0, stream>>>(wih_b, whh_b, bih_b, bhh_b, WCb, bsb, 512);
  k_buildWC<<<4096, 256, 0, stream>>>(wih1, whh1, bih1, bhh1, WC1, bs1, 1024);
  k_buildWC<<<4096, 256, 0, stream>>>(wih2, whh2, bih2, bhh2, WC2, bs2, 1024);
  k_init<<<256, 256, 0, stream>>>(h0f, h0b, h01, h02, XIN, H1, H2);
  k_emb<<<2048, 256, 0, stream>>>(x, emb, Xemb);

  RP P;
  P.WCf = WCf; P.WCb = WCb; P.WC1 = WC1; P.WC2 = WC2;
  P.bsf = bsf; P.bsb = bsb; P.bs1 = bs1; P.bs2 = bs2;
  P.Xemb = Xemb; P.XIN = XIN; P.H1 = H1; P.H2 = H2; P.C2 = C2;
  P.FLC = FLC; P.FLA = FLA; P.FLB = FLB;
  P.c0f = c0f; P.c0b = c0b; P.c02 = c02;
  k_rnn<<<96, 512, 0, stream>>>(P);

  k_logits<<<250, 256, 0, stream>>>(H2 + 128UL * 65536, wlin, blin, (float*)d_out);
}